// Round 3
// baseline (1447.169 us; speedup 1.0000x reference)
//
#include <hip/hip_runtime.h>

#define BATCH   262144
#define NCODE   1024
#define DIM     64
#define BLOCK   256
#define NBLK    (BATCH / BLOCK)   // 1024 blocks
#define KT      16                // codes per k-tile (16 fp32 accumulators/thread)

// ws layout: [0, 8192): double partial[1024]; [8192, 12288): float c2[1024]

// c2[k] = np.sum(cb[k]*cb[k]) with numpy's pairwise order (8 accumulators, n=64)
__global__ void c2_kernel(const float* __restrict__ cb, float* __restrict__ c2) {
    int k = blockIdx.x * blockDim.x + threadIdx.x;
    if (k >= NCODE) return;
    const float* row = cb + (size_t)k * DIM;
    float r[8];
#pragma unroll
    for (int j = 0; j < 8; ++j) r[j] = __fmul_rn(row[j], row[j]);
#pragma unroll
    for (int i = 8; i < DIM; i += 8) {
#pragma unroll
        for (int j = 0; j < 8; ++j) r[j] = __fadd_rn(r[j], __fmul_rn(row[i + j], row[i + j]));
    }
    c2[k] = __fadd_rn(__fadd_rn(__fadd_rn(r[0], r[1]), __fadd_rn(r[2], r[3])),
                      __fadd_rn(__fadd_rn(r[4], r[5]), __fadd_rn(r[6], r[7])));
}

// z-row lives in LDS transposed (z_lds[d][tid], stride 256 words = conflict-free:
// every access is fixed-d with lanes spanning tid -> 2 lanes/bank, free).
// k-tiled with 16 accumulators -> ~30 live VGPRs: un-spillable even at the
// allocator's 48-reg heuristic that sank rounds 1-2 (55 MB scratch writes).
// Numerics: per (b,k) the dot is still a sequential d=0..63 fp32 FMA chain ->
// bit-identical to the round-1 kernel that passed with absmax 0.0.
__global__ __launch_bounds__(BLOCK) void vq_kernel(
        const float* __restrict__ z, const float* __restrict__ cb,
        const float* __restrict__ c2, float* __restrict__ out_zq,
        float* __restrict__ out_idx, double* __restrict__ partial) {
    __shared__ __align__(16) float zsm[DIM * BLOCK];   // 64 KB, [d][tid]
    const int t = threadIdx.x;
    const int b = blockIdx.x * BLOCK + t;

    // stage z row -> LDS transposed; compute z2 with numpy pairwise order
    const float4* zv = (const float4*)(z + (size_t)b * DIM);
    float r[8];
#pragma unroll
    for (int i8 = 0; i8 < 8; ++i8) {
        float4 a = zv[2 * i8];
        float4 c = zv[2 * i8 + 1];
        float e[8] = {a.x, a.y, a.z, a.w, c.x, c.y, c.z, c.w};
#pragma unroll
        for (int j = 0; j < 8; ++j) {
            zsm[(8 * i8 + j) * BLOCK + t] = e[j];
            const float sq = __fmul_rn(e[j], e[j]);
            r[j] = (i8 == 0) ? sq : __fadd_rn(r[j], sq);
        }
    }
    const float z2 = __fadd_rn(__fadd_rn(__fadd_rn(r[0], r[1]), __fadd_rn(r[2], r[3])),
                               __fadd_rn(__fadd_rn(r[4], r[5]), __fadd_rn(r[6], r[7])));
    __syncthreads();

    float best = __builtin_inff();
    int bestk = 0;
    for (int kt = 0; kt < NCODE; kt += KT) {
        float acc[KT];
#pragma unroll
        for (int j = 0; j < KT; ++j) acc[j] = 0.0f;
        const float* cbase = cb + (size_t)kt * DIM;

        // software-pipelined z chunk (LDS latency hidden behind 64 FMAs)
        float zc0 = zsm[0 * BLOCK + t], zc1 = zsm[1 * BLOCK + t];
        float zc2 = zsm[2 * BLOCK + t], zc3 = zsm[3 * BLOCK + t];
#pragma unroll 1
        for (int d = 0; d < DIM; d += 4) {
            float zn0, zn1, zn2, zn3;
            if (d + 4 < DIM) {
                zn0 = zsm[(d + 4) * BLOCK + t];
                zn1 = zsm[(d + 5) * BLOCK + t];
                zn2 = zsm[(d + 6) * BLOCK + t];
                zn3 = zsm[(d + 7) * BLOCK + t];
            }
#pragma unroll
            for (int j = 0; j < KT; ++j) {
                const float* ck = cbase + j * DIM + d;   // wave-uniform -> s_load_dwordx4
                acc[j] = __fmaf_rn(zc0, ck[0], acc[j]);
                acc[j] = __fmaf_rn(zc1, ck[1], acc[j]);
                acc[j] = __fmaf_rn(zc2, ck[2], acc[j]);
                acc[j] = __fmaf_rn(zc3, ck[3], acc[j]);
            }
            zc0 = zn0; zc1 = zn1; zc2 = zn2; zc3 = zn3;
        }
#pragma unroll
        for (int j = 0; j < KT; ++j) {
            const float tt = __fmaf_rn(-2.0f, acc[j], z2);   // == rnd(z2 - 2*acc)
            const float dist = __fadd_rn(tt, c2[kt + j]);
            if (dist < best) { best = dist; bestk = kt + j; }  // strict <: first-index tie
        }
    }

    // epilogue: z_q gather (divergent), straight-through output, loss partial
    const float* cq = cb + (size_t)bestk * DIM;
    double lsum = 0.0;
    float4* ov = (float4*)(out_zq + (size_t)b * DIM);
#pragma unroll
    for (int i = 0; i < DIM / 4; ++i) {
        float q[4], o[4];
#pragma unroll
        for (int j = 0; j < 4; ++j) q[j] = cq[4 * i + j];
#pragma unroll
        for (int j = 0; j < 4; ++j) {
            const float zj = zsm[(4 * i + j) * BLOCK + t];
            const float tt = __fsub_rn(q[j], zj);        // z_q - z (rounded)
            o[j] = __fadd_rn(zj, tt);                    // z + (z_q - z)
            lsum += (double)tt * (double)tt;
        }
        float4 vv; vv.x = o[0]; vv.y = o[1]; vv.z = o[2]; vv.w = o[3];
        ov[i] = vv;
    }
    out_idx[b] = (float)bestk;

    // block-level deterministic loss reduction (reuse zsm as double scratch)
    __syncthreads();                                     // all zsm reads done
    double* sred = (double*)zsm;
    sred[t] = lsum;
    __syncthreads();
#pragma unroll
    for (int s = BLOCK / 2; s > 0; s >>= 1) {
        if (t < s) sred[t] += sred[t + s];
        __syncthreads();
    }
    if (t == 0) partial[blockIdx.x] = sred[0];
}

__global__ void loss_kernel(const double* __restrict__ partial, float* __restrict__ out_loss) {
    __shared__ double sred[256];
    double s = 0.0;
    for (int i = threadIdx.x; i < NBLK; i += 256) s += partial[i];
    sred[threadIdx.x] = s;
    __syncthreads();
#pragma unroll
    for (int st = 128; st > 0; st >>= 1) {
        if (threadIdx.x < st) sred[threadIdx.x] += sred[threadIdx.x + st];
        __syncthreads();
    }
    if (threadIdx.x == 0) {
        const double mean = sred[0] / (double)((size_t)BATCH * DIM);
        const float L = (float)mean;                       // codebook_loss == commitment_loss numerically
        out_loss[0] = __fadd_rn(L, __fmul_rn(0.25f, L));   // L + 0.25*L, fp32 rounding like ref
    }
}

extern "C" void kernel_launch(void* const* d_in, const int* in_sizes, int n_in,
                              void* d_out, int out_size, void* d_ws, size_t ws_size,
                              hipStream_t stream) {
    (void)in_sizes; (void)n_in; (void)out_size; (void)ws_size;
    const float* z  = (const float*)d_in[0];
    const float* cb = (const float*)d_in[1];
    float* out      = (float*)d_out;
    float* out_zq   = out;                                  // [BATCH*DIM)
    float* out_loss = out + (size_t)BATCH * DIM;            // [1]
    float* out_idx  = out + (size_t)BATCH * DIM + 1;        // [BATCH]
    double* partial = (double*)d_ws;                        // 1024 doubles
    float* c2       = (float*)((char*)d_ws + NBLK * sizeof(double));

    c2_kernel<<<NCODE / 256, 256, 0, stream>>>(cb, c2);
    vq_kernel<<<NBLK, BLOCK, 0, stream>>>(z, cb, c2, out_zq, out_idx, partial);
    loss_kernel<<<1, 256, 0, stream>>>(partial, out_loss);
}

// Round 4
// 746.973 us; speedup vs baseline: 1.9374x; 1.9374x over previous
//
#include <hip/hip_runtime.h>

#define BATCH   262144
#define NCODE   1024
#define DIM     64
#define BLOCK   256
#define NBLK    (BATCH / BLOCK)   // 1024 blocks

// ws layout: [0, 8192): double partial[1024]; [8192, 12288): float c2[1024]

// c2[k] = np.sum(cb[k]*cb[k]) with numpy's pairwise order (8 accumulators, n=64)
__global__ void c2_kernel(const float* __restrict__ cb, float* __restrict__ c2) {
    int k = blockIdx.x * blockDim.x + threadIdx.x;
    if (k >= NCODE) return;
    const float* row = cb + (size_t)k * DIM;
    float r[8];
#pragma unroll
    for (int j = 0; j < 8; ++j) r[j] = __fmul_rn(row[j], row[j]);
#pragma unroll
    for (int i = 8; i < DIM; i += 8) {
#pragma unroll
        for (int j = 0; j < 8; ++j) r[j] = __fadd_rn(r[j], __fmul_rn(row[i + j], row[i + j]));
    }
    c2[k] = __fadd_rn(__fadd_rn(__fadd_rn(r[0], r[1]), __fadd_rn(r[2], r[3])),
                      __fadd_rn(__fadd_rn(r[4], r[5]), __fadd_rn(r[6], r[7])));
}

// amdgpu_waves_per_eu(4,4): the MAX field pins the scheduler's occupancy
// target at 4 waves/EU -> 128-VGPR budget -> zr[64] stays in registers.
// __launch_bounds__'s 2nd arg (round 2) only sets the MIN and the scheduler
// still spilled ~55 MB/launch chasing 8 waves/EU (WRITE_SIZE 123 MB vs 68.4
// ideal, VGPR_Count 48). Grid is exactly 4 blocks/CU, so (4,4) loses nothing.
__global__ __launch_bounds__(BLOCK)
__attribute__((amdgpu_waves_per_eu(4, 4)))
void vq_kernel(
        const float* __restrict__ z, const float* __restrict__ cb,
        const float* __restrict__ c2, float* __restrict__ out_zq,
        float* __restrict__ out_idx, double* __restrict__ partial) {
    const int b = blockIdx.x * BLOCK + threadIdx.x;

    // load my row of z into registers (16 x float4)
    float zr[DIM];
    const float4* zv = (const float4*)(z + (size_t)b * DIM);
#pragma unroll
    for (int i = 0; i < DIM / 4; ++i) {
        float4 v = zv[i];
        zr[4 * i + 0] = v.x; zr[4 * i + 1] = v.y;
        zr[4 * i + 2] = v.z; zr[4 * i + 3] = v.w;
    }

    // z2 = np.sum(z*z, axis=1) — numpy pairwise, n=64
    float r[8];
#pragma unroll
    for (int j = 0; j < 8; ++j) r[j] = __fmul_rn(zr[j], zr[j]);
#pragma unroll
    for (int i = 8; i < DIM; i += 8) {
#pragma unroll
        for (int j = 0; j < 8; ++j) r[j] = __fadd_rn(r[j], __fmul_rn(zr[i + j], zr[i + j]));
    }
    const float z2 = __fadd_rn(__fadd_rn(__fadd_rn(r[0], r[1]), __fadd_rn(r[2], r[3])),
                               __fadd_rn(__fadd_rn(r[4], r[5]), __fadd_rn(r[6], r[7])));

    // argmin_k of rnd(rnd(z2 - 2*dot(z,cb_k)) + c2_k); dot = sequential fp32 FMA
    // (sgemm accumulation order — verified bit-exact vs np reference, absmax 0.0).
    // k wave-uniform -> codebook row streams via s_load into SGPRs.
    float best = __builtin_inff();
    int bestk = 0;
    for (int k = 0; k < NCODE; ++k) {
        const float* ck = cb + (size_t)k * DIM;
        float acc = 0.0f;
#pragma unroll
        for (int d = 0; d < DIM; ++d) acc = __fmaf_rn(zr[d], ck[d], acc);
        const float t = __fmaf_rn(-2.0f, acc, z2);        // == rnd(z2 - 2*acc), single rounding
        const float dist = __fadd_rn(t, c2[k]);
        if (dist < best) { best = dist; bestk = k; }      // strict < : first-index tie-break
    }

    // epilogue: z_q gather, straight-through output, loss partial
    const float* cq = cb + (size_t)bestk * DIM;
    double lsum = 0.0;
    float4* ov = (float4*)(out_zq + (size_t)b * DIM);
#pragma unroll
    for (int i = 0; i < DIM / 4; ++i) {
        float q[4], o[4];
#pragma unroll
        for (int j = 0; j < 4; ++j) q[j] = cq[4 * i + j];
#pragma unroll
        for (int j = 0; j < 4; ++j) {
            const float t = __fsub_rn(q[j], zr[4 * i + j]);   // z_q - z (rounded)
            o[j] = __fadd_rn(zr[4 * i + j], t);               // z + (z_q - z)
            lsum += (double)t * (double)t;
        }
        float4 vv; vv.x = o[0]; vv.y = o[1]; vv.z = o[2]; vv.w = o[3];
        ov[i] = vv;
    }
    out_idx[b] = (float)bestk;

    // block-level deterministic loss reduction
    __shared__ double sred[BLOCK];
    sred[threadIdx.x] = lsum;
    __syncthreads();
#pragma unroll
    for (int s = BLOCK / 2; s > 0; s >>= 1) {
        if (threadIdx.x < s) sred[threadIdx.x] += sred[threadIdx.x + s];
        __syncthreads();
    }
    if (threadIdx.x == 0) partial[blockIdx.x] = sred[0];
}

__global__ void loss_kernel(const double* __restrict__ partial, float* __restrict__ out_loss) {
    __shared__ double sred[256];
    double s = 0.0;
    for (int i = threadIdx.x; i < NBLK; i += 256) s += partial[i];
    sred[threadIdx.x] = s;
    __syncthreads();
#pragma unroll
    for (int st = 128; st > 0; st >>= 1) {
        if (threadIdx.x < st) sred[threadIdx.x] += sred[threadIdx.x + st];
        __syncthreads();
    }
    if (threadIdx.x == 0) {
        const double mean = sred[0] / (double)((size_t)BATCH * DIM);
        const float L = (float)mean;                       // codebook_loss == commitment_loss numerically
        out_loss[0] = __fadd_rn(L, __fmul_rn(0.25f, L));   // L + 0.25*L, fp32 rounding like ref
    }
}

extern "C" void kernel_launch(void* const* d_in, const int* in_sizes, int n_in,
                              void* d_out, int out_size, void* d_ws, size_t ws_size,
                              hipStream_t stream) {
    (void)in_sizes; (void)n_in; (void)out_size; (void)ws_size;
    const float* z  = (const float*)d_in[0];
    const float* cb = (const float*)d_in[1];
    float* out      = (float*)d_out;
    float* out_zq   = out;                                  // [BATCH*DIM)
    float* out_loss = out + (size_t)BATCH * DIM;            // [1]
    float* out_idx  = out + (size_t)BATCH * DIM + 1;        // [BATCH]
    double* partial = (double*)d_ws;                        // 1024 doubles
    float* c2       = (float*)((char*)d_ws + NBLK * sizeof(double));

    c2_kernel<<<NCODE / 256, 256, 0, stream>>>(cb, c2);
    vq_kernel<<<NBLK, BLOCK, 0, stream>>>(z, cb, c2, out_zq, out_idx, partial);
    loss_kernel<<<1, 256, 0, stream>>>(partial, out_loss);
}